// Round 5
// baseline (15847.951 us; speedup 1.0000x reference)
//
#include <hip/hip_runtime.h>

#define NB 64      // batch
#define NL 512     // seq len
#define NT 64      // answer len
#define NH 512     // hidden
#define NE 256     // emb dim
#define NW 256     // attention weight dim

typedef __attribute__((ext_vector_type(8))) short bf16x8;
typedef __attribute__((ext_vector_type(4))) float f32x4;
typedef unsigned short u16;
typedef unsigned int u32;
typedef unsigned long long u64;

__device__ __forceinline__ float bf2f(u16 v){
  union { u32 u; float f; } x; x.u = ((u32)v) << 16; return x.f;
}
__device__ __forceinline__ u16 f2bf(float f){
  union { float f; u32 u; } x; x.f = f;
  return (u16)((x.u + 0x7FFFu + ((x.u >> 16) & 1u)) >> 16);
}
__device__ __forceinline__ float sigm(float x){ return 1.f / (1.f + __expf(-x)); }
__device__ __forceinline__ float tanh_(float x){ float e = __expf(2.f * x); return 1.f - 2.f / (e + 1.f); }

// device-scope (L3 coherence point) movement — no fences, no RMW
__device__ __forceinline__ u64 ald64(const u64* p){
  return __hip_atomic_load(p, __ATOMIC_RELAXED, __HIP_MEMORY_SCOPE_AGENT);
}
__device__ __forceinline__ u32 ald32(const u32* p){
  return __hip_atomic_load(p, __ATOMIC_RELAXED, __HIP_MEMORY_SCOPE_AGENT);
}
__device__ __forceinline__ void ast32(u32* p, u32 v){
  __hip_atomic_store(p, v, __ATOMIC_RELAXED, __HIP_MEMORY_SCOPE_AGENT);
}
__device__ __forceinline__ bf16x8 mk8(u64 a, u64 b){
  union { u64 q[2]; bf16x8 v; } u; u.q[0] = a; u.q[1] = b; return u.v;
}
// all of this block's stores have reached the coherence point
__device__ __forceinline__ void drain_stores(){
  asm volatile("s_waitcnt vmcnt(0)" ::: "memory");
  __syncthreads();
}

__global__ void init_kernel(int* cnt){
  cnt[blockIdx.x * 256 + threadIdx.x] = 0;
}

// fp32 -> bf16 (round-to-nearest-even)
__global__ void cvt_kernel(const float* __restrict__ src, u16* __restrict__ dst, int n){
  const int i = blockIdx.x * 256 + threadIdx.x;
  if(i < n) dst[i] = f2bf(src[i]);
}

// ---------------------------------------------------------------------------
// Encoder: persistent, 32 blocks x 256 threads = 128 waves.
// btile = blockIdx&3 (independent group of 8 blocks), mtile = (blockIdx>>2)*4
// + wave. Wave computes 16(batch) x 16(hidden) of all 4 gates; cell state in
// registers; h in a 3-slot device ring (atomic stores/loads). Sync per step:
// each block STORES t+1 into its own 64B-padded flag word; every wave polls
// its group's 8 flag lines (lanes<8 gather + ballot, s_sleep backoff).
// No atomic RMW anywhere. x-part of t+1 overlaps the poll; emb is fp32,
// converted to bf16 in registers.
// ---------------------------------------------------------------------------
__global__ void __launch_bounds__(256, 1) enc_kernel(
    const int* __restrict__ ids, const float* __restrict__ emb,
    const u16* __restrict__ Wih, const u16* __restrict__ Whh,
    const float* __restrict__ bih, const float* __restrict__ bhh,
    const u16* __restrict__ W1,  const float* __restrict__ b1,
    u16* hroll, u16* bl, u32* flags)
{
  const int lane = threadIdx.x & 63;
  const int col  = lane & 15;
  const int quad = lane >> 4;
  const int btile = blockIdx.x & 3;
  const int blk   = blockIdx.x >> 2;      // 0..7 within group
  const int mtile = blk * 4 + (threadIdx.x >> 6);
  const int j  = mtile * 16 + col;        // hidden index within a gate [0,512)
  const int ab = btile * 16 + col;        // A-row (batch) this lane loads
  u32* myflag = flags + (btile * 8 + blk) * 16;   // own 64B line
  const u32* fgrp = flags + btile * 8 * 16;       // group's 8 lines

  float bias[4];
  const u16* wh[4];
  const u16* wx[4];
#pragma unroll
  for(int g = 0; g < 4; ++g){
    const int row = g * NH + j;           // PyTorch gate order i,f,g,o
    bias[g] = bih[row] + bhh[row];
    wh[g] = Whh + (size_t)row * NH + quad * 8;
    wx[g] = Wih + (size_t)row * NE + quad * 8;
  }
  const int* idp = ids + ab * NL;         // ids is [B, L]
  const int n1 = mtile * 16 + col;        // blend1 column (mtile<16 only)
  const u16* w1r = W1 + (size_t)(mtile < 16 ? n1 : 0) * NH + quad * 8;
  const float b1f = (mtile < 16) ? b1[n1] : 0.f;
  float creg[4] = {0.f, 0.f, 0.f, 0.f};   // cell state, lane-owned

  u64 hb[32];                             // h_{t-1} fragment
  f32x4 acc[4];

  // x-part of t=0 (fp32 emb -> bf16 regs)
  {
    const float* xr = emb + (size_t)idp[0] * NE + quad * 8;
#pragma unroll
    for(int g = 0; g < 4; ++g) acc[g] = (f32x4){0.f, 0.f, 0.f, 0.f};
#pragma unroll
    for(int k0 = 0; k0 < NE; k0 += 32){
      const f32x4 a0 = *(const f32x4*)(xr + k0);
      const f32x4 a1 = *(const f32x4*)(xr + k0 + 4);
      bf16x8 af;
#pragma unroll
      for(int q = 0; q < 4; ++q){ af[q] = (short)f2bf(a0[q]); af[q + 4] = (short)f2bf(a1[q]); }
#pragma unroll
      for(int g = 0; g < 4; ++g)
        acc[g] = __builtin_amdgcn_mfma_f32_16x16x32_bf16(af, *(const bf16x8*)(wx[g] + k0), acc[g], 0, 0, 0);
    }
  }

  for(int t = 0; t < NL; ++t){
    // h part (hb = h_{t-1}, loaded at end of previous iteration)
    if(t > 0){
#pragma unroll
      for(int i = 0; i < 16; ++i){
        const bf16x8 af = mk8(hb[2 * i], hb[2 * i + 1]);
#pragma unroll
        for(int g = 0; g < 4; ++g)
          acc[g] = __builtin_amdgcn_mfma_f32_16x16x32_bf16(af, *(const bf16x8*)(wh[g] + 32 * i), acc[g], 0, 0, 0);
      }
    }
    // epilogue: gates -> c (registers), h_t -> hroll[t%3] via atomic stores
    u16* ho = hroll + (t % 3) * (NB * NH);
#pragma unroll
    for(int r = 0; r < 4; ++r){
      const float gi = acc[0][r] + bias[0];
      const float gf = acc[1][r] + bias[1];
      const float gg = acc[2][r] + bias[2];
      const float go = acc[3][r] + bias[3];
      creg[r] = sigm(gf) * creg[r] + sigm(gi) * tanh_(gg);
      const u32 my = f2bf(sigm(go) * tanh_(creg[r]));
      const u32 ot = (u32)__shfl_xor((int)my, 1, 64);
      if((lane & 1) == 0){
        const int row = btile * 16 + quad * 4 + r;
        ast32((u32*)(ho + (size_t)row * NH + j), my | (ot << 16));
      }
    }
    drain_stores();                       // h_t at coherence point
    if(threadIdx.x == 0) ast32(myflag, (u32)(t + 1));   // signal (plain store)

    // overlap: x-part of t+1 while the group finishes
    if(t + 1 < NL){
      const float* xr = emb + (size_t)idp[t + 1] * NE + quad * 8;
#pragma unroll
      for(int g = 0; g < 4; ++g) acc[g] = (f32x4){0.f, 0.f, 0.f, 0.f};
#pragma unroll
      for(int k0 = 0; k0 < NE; k0 += 32){
        const f32x4 a0 = *(const f32x4*)(xr + k0);
        const f32x4 a1 = *(const f32x4*)(xr + k0 + 4);
        bf16x8 af;
#pragma unroll
        for(int q = 0; q < 4; ++q){ af[q] = (short)f2bf(a0[q]); af[q + 4] = (short)f2bf(a1[q]); }
#pragma unroll
        for(int g = 0; g < 4; ++g)
          acc[g] = __builtin_amdgcn_mfma_f32_16x16x32_bf16(af, *(const bf16x8*)(wx[g] + k0), acc[g], 0, 0, 0);
      }
    }
    // poll: every wave gathers the 8 group flags (lanes<8), ballot, backoff
    for(;;){
      const u32 f = (lane < 8) ? ald32(fgrp + lane * 16) : 0xFFFFFFFFu;
      if(__ballot((lane >= 8) || (f >= (u32)(t + 1))) == ~0ull) break;
      __builtin_amdgcn_s_sleep(2);
    }

    // load h_t fragment (used by blend(t) now and h-part(t+1) next iter)
    {
      const u16* ha = hroll + (t % 3) * (NB * NH) + (size_t)ab * NH + quad * 8;
#pragma unroll
      for(int i = 0; i < 16; ++i){
        const u64* p = (const u64*)(ha + 32 * i);
        hb[2 * i]     = ald64(p);
        hb[2 * i + 1] = ald64(p + 1);
      }
    }
    // blend1[t] fold (normal stores — consumed only after kernel end)
    if(mtile < 16){
      f32x4 a2 = {0.f, 0.f, 0.f, 0.f};
#pragma unroll
      for(int i = 0; i < 16; ++i)
        a2 = __builtin_amdgcn_mfma_f32_16x16x32_bf16(mk8(hb[2 * i], hb[2 * i + 1]), *(const bf16x8*)(w1r + 32 * i), a2, 0, 0, 0);
#pragma unroll
      for(int r = 0; r < 4; ++r){
        const int b = btile * 16 + quad * 4 + r;
        bl[((size_t)t * NB + b) * NW + n1] = f2bf(a2[r] + b1f);
      }
    }
  }
}

// ---------------------------------------------------------------------------
// Decoder: persistent, 64 blocks x 256 threads.
// h ring has 65 slots (slot i = h_{i-1}; slot 0 pre-staged bf16(h0)) so there
// is ZERO backpressure sync. Per step: producers (blocks 0..31) read slot t,
// compute h_t, atomic-store into slot t+1, drain, store flag=t+1 (own 64B
// line). All 64 blocks poll the 32 flag lines (lanes<32 + ballot + backoff),
// stage h[myb] through LDS, attention + log-softmax, write out column t.
// ---------------------------------------------------------------------------
__global__ void __launch_bounds__(256, 1) dec_kernel(
    const u16* __restrict__ Whh, const float* __restrict__ bih, const float* __restrict__ bhh,
    const float* __restrict__ W2, const float* __restrict__ b2,
    const float* __restrict__ vt, const float* __restrict__ vtb,
    const u16* __restrict__ bl,  const u16* __restrict__ hroll,
    u16* hdec, float* out, u32* flags)
{
  const int tid  = threadIdx.x;
  const int lane = tid & 63;
  const int wvl  = tid >> 6;
  const int col  = lane & 15;
  const int quad = lane >> 4;
  const int myb  = blockIdx.x;
  const bool producer = (blockIdx.x < 32);
  u32* myflag = flags + blockIdx.x * 16;

  __shared__ u64  hld[NH / 4];   // this block's h row (1 KB)
  __shared__ float u_lds[NW];
  __shared__ float vt_lds[NW];
  __shared__ float s_lds[NL];
  __shared__ float red[8];

  const int gw   = blockIdx.x * 4 + wvl;
  const int btile = gw >> 5;
  const int mtile = gw & 31;
  const int j  = mtile * 16 + col;
  const int ab = btile * 16 + col;
  float bias[4] = {0.f, 0.f, 0.f, 0.f};
  const u16* wh[4] = {Whh, Whh, Whh, Whh};
  float creg[4] = {0.f, 0.f, 0.f, 0.f};
  if(producer){
#pragma unroll
    for(int g = 0; g < 4; ++g){
      const int row = g * NH + j;
      bias[g] = bih[row] + bhh[row];
      wh[g] = Whh + (size_t)row * NH + quad * 8;
    }
    // c0 = enc h_511, in hroll slot 511%3 == 1 (normal loads: kernel boundary)
#pragma unroll
    for(int r = 0; r < 4; ++r){
      const int ci = (btile * 16 + quad * 4 + r) * NH + j;
      creg[r] = bf2f(hroll[(NB * NH) + ci]);
    }
  }
  vt_lds[tid] = vt[tid];
  const float vtbf = vtb[0];
  const float* w2r = W2 + (size_t)tid * NH;
  const float b2f = b2[tid];

  for(int t = 0; t < NT; ++t){
    if(producer){
      // h_{t-1} = slot t (slot 0 pre-staged with bf16(h0))
      u64 hb[32];
      {
        const u16* hp = hdec + (size_t)t * (NB * NH) + (size_t)ab * NH + quad * 8;
#pragma unroll
        for(int i = 0; i < 16; ++i){
          const u64* p = (const u64*)(hp + 32 * i);
          hb[2 * i]     = ald64(p);
          hb[2 * i + 1] = ald64(p + 1);
        }
      }
      f32x4 z = {0.f, 0.f, 0.f, 0.f};
      f32x4 acc[4] = {z, z, z, z};
#pragma unroll
      for(int i = 0; i < 16; ++i){
        const bf16x8 af = mk8(hb[2 * i], hb[2 * i + 1]);
#pragma unroll
        for(int g = 0; g < 4; ++g)
          acc[g] = __builtin_amdgcn_mfma_f32_16x16x32_bf16(af, *(const bf16x8*)(wh[g] + 32 * i), acc[g], 0, 0, 0);
      }
      u16* hn = hdec + (size_t)(t + 1) * (NB * NH);
#pragma unroll
      for(int r = 0; r < 4; ++r){
        const float gi = acc[0][r] + bias[0];
        const float gf = acc[1][r] + bias[1];
        const float gg = acc[2][r] + bias[2];
        const float go = acc[3][r] + bias[3];
        creg[r] = sigm(gf) * creg[r] + sigm(gi) * tanh_(gg);
        const u32 my = f2bf(sigm(go) * tanh_(creg[r]));
        const u32 ot = (u32)__shfl_xor((int)my, 1, 64);
        if((lane & 1) == 0){
          const int row = btile * 16 + quad * 4 + r;
          ast32((u32*)(hn + (size_t)row * NH + j), my | (ot << 16));
        }
      }
      drain_stores();
      if(tid == 0) ast32(myflag, (u32)(t + 1));
    }

    // ---- all blocks: poll the 32 producer flags, then attention ----
    for(;;){
      const u32 f = (lane < 32) ? ald32(flags + lane * 16) : 0xFFFFFFFFu;
      if(__ballot((lane >= 32) || (f >= (u32)(t + 1))) == ~0ull) break;
      __builtin_amdgcn_s_sleep(2);
    }
    __syncthreads();
    if(tid < NH / 4)
      hld[tid] = ald64((const u64*)(hdec + (size_t)(t + 1) * (NB * NH) + (size_t)myb * NH) + tid);
    __syncthreads();

    // u[tid] = b2[tid] + h . W2[tid,:]
    {
      float s = b2f;
#pragma unroll 8
      for(int kk = 0; kk < NH / 4; ++kk){
        const u64 v = hld[kk];
        s += bf2f((u16)(v      )) * w2r[kk * 4    ];
        s += bf2f((u16)(v >> 16)) * w2r[kk * 4 + 1];
        s += bf2f((u16)(v >> 32)) * w2r[kk * 4 + 2];
        s += bf2f((u16)(v >> 48)) * w2r[kk * 4 + 3];
      }
      u_lds[tid] = s;
    }
    __syncthreads();

    for(int l = wvl; l < NL; l += 4){
      const u16* br = bl + (size_t)(l * NB + myb) * NW;
      float p = 0.f;
#pragma unroll
      for(int q = 0; q < 4; ++q){
        const int w = lane + 64 * q;
        p += vt_lds[w] * tanh_(bf2f(br[w]) + u_lds[w]);
      }
#pragma unroll
      for(int off = 32; off > 0; off >>= 1) p += __shfl_xor(p, off, 64);
      if(lane == 0) s_lds[l] = p + vtbf;
    }
    __syncthreads();

    // log-softmax over L = 512 (thread owns l = tid and tid+256)
    const float a0 = s_lds[tid];
    const float a1 = s_lds[tid + 256];
    float mx = fmaxf(a0, a1);
#pragma unroll
    for(int off = 32; off > 0; off >>= 1) mx = fmaxf(mx, __shfl_xor(mx, off, 64));
    if(lane == 0) red[wvl] = mx;
    __syncthreads();
    mx = fmaxf(fmaxf(red[0], red[1]), fmaxf(red[2], red[3]));
    float es = __expf(a0 - mx) + __expf(a1 - mx);
#pragma unroll
    for(int off = 32; off > 0; off >>= 1) es += __shfl_xor(es, off, 64);
    if(lane == 0) red[4 + wvl] = es;
    __syncthreads();
    const float lse = mx + logf(red[4] + red[5] + red[6] + red[7]);
    out[((size_t)tid * NB + myb) * NT + t]         = a0 - lse;
    out[((size_t)(tid + 256) * NB + myb) * NT + t] = a1 - lse;
    __syncthreads();
  }
}

// ---------------------------------------------------------------------------
extern "C" void kernel_launch(void* const* d_in, const int* in_sizes, int n_in,
                              void* d_out, int out_size, void* d_ws, size_t ws_size,
                              hipStream_t stream)
{
  (void)in_sizes; (void)n_in; (void)out_size; (void)ws_size;
  const int*   ids  = (const int*)d_in[0];
  const float* emb  = (const float*)d_in[1];
  const float* eWih = (const float*)d_in[2];
  const float* eWhh = (const float*)d_in[3];
  const float* ebih = (const float*)d_in[4];
  const float* ebhh = (const float*)d_in[5];
  /* d_in[6] = dec_Wih: unused (decoder input is identically zero) */
  const float* dWhh = (const float*)d_in[7];
  const float* dbih = (const float*)d_in[8];
  const float* dbhh = (const float*)d_in[9];
  const float* W1   = (const float*)d_in[10];
  const float* b1   = (const float*)d_in[11];
  const float* W2   = (const float*)d_in[12];
  const float* b2   = (const float*)d_in[13];
  const float* vt   = (const float*)d_in[14];
  const float* vtb  = (const float*)d_in[15];
  const float* h0   = (const float*)d_in[16];

  // workspace: ~26.8 MB (within the proven envelope)
  char* ws = (char*)d_ws;
  u16* bl     = (u16*)ws; ws += (size_t)NL * NB * NW * 2;        // blend1 bf16   16.78 MB
  u16* hroll  = (u16*)ws; ws += (size_t)3 * NB * NH * 2;         // enc h ring    0.20 MB
  u16* hdec   = (u16*)ws; ws += (size_t)(NT + 1) * NB * NH * 2;  // dec h ring    4.26 MB
  u16* eWih_b = (u16*)ws; ws += (size_t)4 * NH * NE * 2;         // 1.05 MB
  u16* eWhh_b = (u16*)ws; ws += (size_t)4 * NH * NH * 2;         // 2.10 MB
  u16* dWhh_b = (u16*)ws; ws += (size_t)4 * NH * NH * 2;         // 2.10 MB
  u16* W1_b   = (u16*)ws; ws += (size_t)NW * NH * 2;             // 0.26 MB
  u32* flags  = (u32*)ws;                                        // 1024 u32 (64B-padded flags)

  hipLaunchKernelGGL(init_kernel, dim3(4), dim3(256), 0, stream, (int*)flags);
  hipLaunchKernelGGL(cvt_kernel, dim3((4 * NH * NE + 255) / 256), dim3(256), 0, stream, eWih, eWih_b, 4 * NH * NE);
  hipLaunchKernelGGL(cvt_kernel, dim3((4 * NH * NH + 255) / 256), dim3(256), 0, stream, eWhh, eWhh_b, 4 * NH * NH);
  hipLaunchKernelGGL(cvt_kernel, dim3((4 * NH * NH + 255) / 256), dim3(256), 0, stream, dWhh, dWhh_b, 4 * NH * NH);
  hipLaunchKernelGGL(cvt_kernel, dim3((NW * NH + 255) / 256), dim3(256), 0, stream, W1,   W1_b,   NW * NH);
  hipLaunchKernelGGL(cvt_kernel, dim3((NB * NH + 255) / 256), dim3(256), 0, stream, h0, hdec, NB * NH);  // slot 0 = bf16(h0)

  hipLaunchKernelGGL(enc_kernel, dim3(32), dim3(256), 0, stream,
                     ids, emb, eWih_b, eWhh_b, ebih, ebhh, W1_b, b1, hroll, bl, flags);
  hipLaunchKernelGGL(dec_kernel, dim3(64), dim3(256), 0, stream,
                     dWhh_b, dbih, dbhh, W2, b2, vt, vtb, bl, hroll, hdec,
                     (float*)d_out, flags + 512);
}

// Round 6
// 15200.853 us; speedup vs baseline: 1.0426x; 1.0426x over previous
//
#include <hip/hip_runtime.h>

#define NB 64      // batch
#define NL 512     // seq len
#define NT 64      // answer len
#define NH 512     // hidden
#define NE 256     // emb dim
#define NW 256     // attention weight dim

typedef __attribute__((ext_vector_type(8))) short bf16x8;
typedef __attribute__((ext_vector_type(4))) float f32x4;
typedef unsigned short u16;
typedef unsigned int u32;
typedef unsigned long long u64;

#define STM 0x4000400040004000ull   // bit14 of each u16 (never set in bf16 of |v|<2)
#define CLRM 0xBFFFBFFFBFFFBFFFull

__device__ __forceinline__ float bf2f(u16 v){
  union { u32 u; float f; } x; x.u = ((u32)v) << 16; return x.f;
}
__device__ __forceinline__ u16 f2bf(float f){
  union { float f; u32 u; } x; x.f = f;
  return (u16)((x.u + 0x7FFFu + ((x.u >> 16) & 1u)) >> 16);
}
__device__ __forceinline__ float sigm(float x){ return 1.f / (1.f + __expf(-x)); }
__device__ __forceinline__ float tanh_(float x){ float e = __expf(2.f * x); return 1.f - 2.f / (e + 1.f); }

// device-scope (L3 coherence point) loads/stores — poll-on-data, no fences
__device__ __forceinline__ u64 ald64(const u64* p){
  return __hip_atomic_load(p, __ATOMIC_RELAXED, __HIP_MEMORY_SCOPE_AGENT);
}
__device__ __forceinline__ void ast64(u64* p, u64 v){
  __hip_atomic_store(p, v, __ATOMIC_RELAXED, __HIP_MEMORY_SCOPE_AGENT);
}
__device__ __forceinline__ bf16x8 mk8(u64 a, u64 b){
  union { u64 q[2]; bf16x8 v; } u; u.q[0] = a; u.q[1] = b; return u.v;
}

__global__ void fill_kernel(u32* p, u32 v){
  p[blockIdx.x * 256 + threadIdx.x] = v;
}

// fp32 -> bf16 (round-to-nearest-even)
__global__ void cvt_kernel(const float* __restrict__ src, u16* __restrict__ dst, int n){
  const int i = blockIdx.x * 256 + threadIdx.x;
  if(i < n) dst[i] = f2bf(src[i]);
}

// ---------------------------------------------------------------------------
// Encoder: persistent, 32 blocks x 256 threads = 128 waves, 4 independent
// btile groups of 8 blocks. Wave computes 16(batch) x 16(hidden) of all 4
// gates; cell state in registers. h in a 2-slot ring; each stored u16 is
// STAMPED in bit14 with parity (t>>1)&1; consumers poll the data itself until
// every u16 carries the expected stamp (one visibility hop, no flags/drains).
// Overwrite-safe: producing t requires having seen all of t-1, which proves
// all blocks consumed t-2 (the ring depth).
// ---------------------------------------------------------------------------
__global__ void __launch_bounds__(256, 1) enc_kernel(
    const int* __restrict__ ids, const u16* __restrict__ emb,
    const u16* __restrict__ Wih, const u16* __restrict__ Whh,
    const float* __restrict__ bih, const float* __restrict__ bhh,
    const u16* __restrict__ W1,  const float* __restrict__ b1,
    u16* hroll, u16* bl)
{
  const int lane = threadIdx.x & 63;
  const int col  = lane & 15;
  const int quad = lane >> 4;
  const int btile = blockIdx.x & 3;
  const int mtile = (blockIdx.x >> 2) * 4 + (threadIdx.x >> 6);
  const int j  = mtile * 16 + col;        // hidden index within a gate [0,512)
  const int ab = btile * 16 + col;        // A-row (batch) this lane loads

  float bias[4];
  const u16* wh[4];
  const u16* wx[4];
#pragma unroll
  for(int g = 0; g < 4; ++g){
    const int row = g * NH + j;           // PyTorch gate order i,f,g,o
    bias[g] = bih[row] + bhh[row];
    wh[g] = Whh + (size_t)row * NH + quad * 8;
    wx[g] = Wih + (size_t)row * NE + quad * 8;
  }
  const int* idp = ids + ab * NL;         // ids is [B, L]
  const int n1 = mtile * 16 + col;        // blend1 column (mtile<16 only)
  const u16* w1r = W1 + (size_t)(mtile < 16 ? n1 : 0) * NH + quad * 8;
  const float b1f = (mtile < 16) ? b1[n1] : 0.f;
  float creg[4] = {0.f, 0.f, 0.f, 0.f};   // cell state, lane-owned

  u64 hb[32];                             // h_t fragment (stamped-cleaned)
  f32x4 acc[4];

  // x-part of t=0
  {
    const u16* xr = emb + (size_t)idp[0] * NE + quad * 8;
#pragma unroll
    for(int g = 0; g < 4; ++g) acc[g] = (f32x4){0.f, 0.f, 0.f, 0.f};
#pragma unroll
    for(int k0 = 0; k0 < NE; k0 += 32){
      const bf16x8 af = *(const bf16x8*)(xr + k0);
#pragma unroll
      for(int g = 0; g < 4; ++g)
        acc[g] = __builtin_amdgcn_mfma_f32_16x16x32_bf16(af, *(const bf16x8*)(wx[g] + k0), acc[g], 0, 0, 0);
    }
  }

  for(int t = 0; t < NL; ++t){
    // h part (hb = h_{t-1}, loaded by last iteration's poll)
    if(t > 0){
#pragma unroll
      for(int i = 0; i < 16; ++i){
        const bf16x8 af = mk8(hb[2 * i], hb[2 * i + 1]);
#pragma unroll
        for(int g = 0; g < 4; ++g)
          acc[g] = __builtin_amdgcn_mfma_f32_16x16x32_bf16(af, *(const bf16x8*)(wh[g] + 32 * i), acc[g], 0, 0, 0);
      }
    }
    // epilogue: gates -> c (regs); h_t stamped + packed to u64 -> slot t&1
    const u32 st14 = ((u32)((t >> 1) & 1)) << 14;
    u16* ho = hroll + (t & 1) * (NB * NH);
#pragma unroll
    for(int r = 0; r < 4; ++r){
      const float gi = acc[0][r] + bias[0];
      const float gf = acc[1][r] + bias[1];
      const float gg = acc[2][r] + bias[2];
      const float go = acc[3][r] + bias[3];
      creg[r] = sigm(gf) * creg[r] + sigm(gi) * tanh_(gg);
      const u32 stv  = (u32)f2bf(sigm(go) * tanh_(creg[r])) | st14;
      const u32 pair = stv | (((u32)__shfl_xor((int)stv, 1, 64)) << 16);
      const u32 hi   = (u32)__shfl_xor((int)pair, 2, 64);
      if((col & 3) == 0){
        const int row = btile * 16 + quad * 4 + r;
        ast64((u64*)(ho + (size_t)row * NH + mtile * 16 + col),
              (u64)pair | ((u64)hi << 32));
      }
    }
    // overlap: x-part of t+1 while stores become visible
    if(t + 1 < NL){
      const u16* xr = emb + (size_t)idp[t + 1] * NE + quad * 8;
#pragma unroll
      for(int g = 0; g < 4; ++g) acc[g] = (f32x4){0.f, 0.f, 0.f, 0.f};
#pragma unroll
      for(int k0 = 0; k0 < NE; k0 += 32){
        const bf16x8 af = *(const bf16x8*)(xr + k0);
#pragma unroll
        for(int g = 0; g < 4; ++g)
          acc[g] = __builtin_amdgcn_mfma_f32_16x16x32_bf16(af, *(const bf16x8*)(wx[g] + k0), acc[g], 0, 0, 0);
      }
    }
    // poll-on-data: load h_t fragment until every u16 has this step's stamp
    {
      const u16* ha = hroll + (t & 1) * (NB * NH) + (size_t)ab * NH + quad * 8;
      const u64 want = ((t >> 1) & 1) ? STM : 0ull;
      for(;;){
        bool ok = true;
#pragma unroll
        for(int i = 0; i < 16; ++i){
          const u64* p = (const u64*)(ha + 32 * i);
          hb[2 * i]     = ald64(p);
          hb[2 * i + 1] = ald64(p + 1);
          ok = ok && ((hb[2 * i] & STM) == want) && ((hb[2 * i + 1] & STM) == want);
        }
        if(__ballot(ok) == ~0ull) break;
        __builtin_amdgcn_s_sleep(1);
      }
#pragma unroll
      for(int i = 0; i < 32; ++i) hb[i] &= CLRM;
    }
    // blend1[t] fold (normal stores — consumed after kernel boundary)
    if(mtile < 16){
      f32x4 a2 = {0.f, 0.f, 0.f, 0.f};
#pragma unroll
      for(int i = 0; i < 16; ++i)
        a2 = __builtin_amdgcn_mfma_f32_16x16x32_bf16(mk8(hb[2 * i], hb[2 * i + 1]), *(const bf16x8*)(w1r + 32 * i), a2, 0, 0, 0);
#pragma unroll
      for(int r = 0; r < 4; ++r){
        const int b = btile * 16 + quad * 4 + r;
        bl[((size_t)t * NB + b) * NW + n1] = f2bf(a2[r] + b1f);
      }
    }
  }
}

// ---------------------------------------------------------------------------
// Decoder: persistent, 64 blocks x 256 threads. 64 write-once h slots (slot
// t+1 = h_t), stamp bit14 == 1 on every stored u16; initial slot bytes are
// leftover bf16 emb values (|v|<2 => stamp 0), so no init needed. t=0 reads
// fp32 h0 directly. Producers (blocks 0..31) poll slot t, compute, store
// slot t+1. All 64 blocks: wave 0 polls row myb of slot t+1, stages (masked)
// into LDS; then attention + log-softmax, write out column t.
// ---------------------------------------------------------------------------
__global__ void __launch_bounds__(256, 1) dec_kernel(
    const u16* __restrict__ Whh, const float* __restrict__ bih, const float* __restrict__ bhh,
    const float* __restrict__ W2, const float* __restrict__ b2,
    const float* __restrict__ vt, const float* __restrict__ vtb,
    const u16* __restrict__ bl,  const u16* __restrict__ hroll,
    const float* __restrict__ h0f,
    u16* hdX, float* out)
{
  const int tid  = threadIdx.x;
  const int lane = tid & 63;
  const int wvl  = tid >> 6;
  const int col  = lane & 15;
  const int quad = lane >> 4;
  const int myb  = blockIdx.x;
  const bool producer = (blockIdx.x < 32);

  __shared__ u64  hld[NH / 4];   // this block's h row (1 KB)
  __shared__ float u_lds[NW];
  __shared__ float vt_lds[NW];
  __shared__ float s_lds[NL];
  __shared__ float red[8];

  const int gw   = blockIdx.x * 4 + wvl;
  const int btile = gw >> 5;
  const int mtile = gw & 31;
  const int j  = mtile * 16 + col;
  const int ab = btile * 16 + col;
  float bias[4] = {0.f, 0.f, 0.f, 0.f};
  const u16* wh[4] = {Whh, Whh, Whh, Whh};
  float creg[4] = {0.f, 0.f, 0.f, 0.f};
  if(producer){
#pragma unroll
    for(int g = 0; g < 4; ++g){
      const int row = g * NH + j;
      bias[g] = bih[row] + bhh[row];
      wh[g] = Whh + (size_t)row * NH + quad * 8;
    }
    // c0 = enc h_511: hroll slot 511&1 == 1, stamped with (511>>1)&1 == 1
#pragma unroll
    for(int r = 0; r < 4; ++r){
      const int ci = (btile * 16 + quad * 4 + r) * NH + j;
      creg[r] = bf2f((u16)(hroll[(NB * NH) + ci] & 0xBFFFu));
    }
  }
  vt_lds[tid] = vt[tid];
  const float vtbf = vtb[0];
  const float* w2r = W2 + (size_t)tid * NH;
  const float b2f = b2[tid];

  for(int t = 0; t < NT; ++t){
    if(producer){
      f32x4 z = {0.f, 0.f, 0.f, 0.f};
      f32x4 acc[4] = {z, z, z, z};
      if(t == 0){
        // h_{-1} = h0 (fp32, convert in regs)
        const float* hp = h0f + (size_t)ab * NH + quad * 8;
#pragma unroll
        for(int i = 0; i < 16; ++i){
          const f32x4 a0 = *(const f32x4*)(hp + 32 * i);
          const f32x4 a1 = *(const f32x4*)(hp + 32 * i + 4);
          bf16x8 af;
#pragma unroll
          for(int q = 0; q < 4; ++q){ af[q] = (short)f2bf(a0[q]); af[q + 4] = (short)f2bf(a1[q]); }
#pragma unroll
          for(int g = 0; g < 4; ++g)
            acc[g] = __builtin_amdgcn_mfma_f32_16x16x32_bf16(af, *(const bf16x8*)(wh[g] + 32 * i), acc[g], 0, 0, 0);
        }
      } else {
        // poll-on-data: slot t (stamp always 1)
        u64 hb[32];
        const u16* ha = hdX + (size_t)(t - 1) * (NB * NH) + (size_t)ab * NH + quad * 8;
        for(;;){
          bool ok = true;
#pragma unroll
          for(int i = 0; i < 16; ++i){
            const u64* p = (const u64*)(ha + 32 * i);
            hb[2 * i]     = ald64(p);
            hb[2 * i + 1] = ald64(p + 1);
            ok = ok && ((hb[2 * i] & STM) == STM) && ((hb[2 * i + 1] & STM) == STM);
          }
          if(__ballot(ok) == ~0ull) break;
          __builtin_amdgcn_s_sleep(1);
        }
#pragma unroll
        for(int i = 0; i < 16; ++i){
          const bf16x8 af = mk8(hb[2 * i] & CLRM, hb[2 * i + 1] & CLRM);
#pragma unroll
          for(int g = 0; g < 4; ++g)
            acc[g] = __builtin_amdgcn_mfma_f32_16x16x32_bf16(af, *(const bf16x8*)(wh[g] + 32 * i), acc[g], 0, 0, 0);
        }
      }
      // epilogue: store h_t stamped into slot t+1
      u16* hn = hdX + (size_t)t * (NB * NH);
#pragma unroll
      for(int r = 0; r < 4; ++r){
        const float gi = acc[0][r] + bias[0];
        const float gf = acc[1][r] + bias[1];
        const float gg = acc[2][r] + bias[2];
        const float go = acc[3][r] + bias[3];
        creg[r] = sigm(gf) * creg[r] + sigm(gi) * tanh_(gg);
        const u32 stv  = (u32)f2bf(sigm(go) * tanh_(creg[r])) | 0x4000u;
        const u32 pair = stv | (((u32)__shfl_xor((int)stv, 1, 64)) << 16);
        const u32 hi   = (u32)__shfl_xor((int)pair, 2, 64);
        if((col & 3) == 0){
          const int row = btile * 16 + quad * 4 + r;
          ast64((u64*)(hn + (size_t)row * NH + mtile * 16 + col),
                (u64)pair | ((u64)hi << 32));
        }
      }
    }

    // ---- all blocks: wave 0 polls row myb of slot t+1, stages into LDS ----
    if(wvl == 0){
      const u16* hr = hdX + (size_t)t * (NB * NH) + (size_t)myb * NH;
      const u64* hp = (const u64*)hr;
      u64 a, b;
      for(;;){
        a = ald64(hp + lane);
        b = ald64(hp + 64 + lane);
        const bool ok = ((a & STM) == STM) && ((b & STM) == STM);
        if(__ballot(ok) == ~0ull) break;
        __builtin_amdgcn_s_sleep(1);
      }
      hld[lane]      = a & CLRM;
      hld[lane + 64] = b & CLRM;
    }
    __syncthreads();

    // u[tid] = b2[tid] + h . W2[tid,:]
    {
      float s = b2f;
#pragma unroll 8
      for(int kk = 0; kk < NH / 4; ++kk){
        const u64 v = hld[kk];
        s += bf2f((u16)(v      )) * w2r[kk * 4    ];
        s += bf2f((u16)(v >> 16)) * w2r[kk * 4 + 1];
        s += bf2f((u16)(v >> 32)) * w2r[kk * 4 + 2];
        s += bf2f((u16)(v >> 48)) * w2r[kk * 4 + 3];
      }
      u_lds[tid] = s;
    }
    __syncthreads();

    for(int l = wvl; l < NL; l += 4){
      const u16* br = bl + (size_t)(l * NB + myb) * NW;
      float p = 0.f;
#pragma unroll
      for(int q = 0; q < 4; ++q){
        const int w = lane + 64 * q;
        p += vt_lds[w] * tanh_(bf2f(br[w]) + u_lds[w]);
      }
#pragma unroll
      for(int off = 32; off > 0; off >>= 1) p += __shfl_xor(p, off, 64);
      if(lane == 0) s_lds[l] = p + vtbf;
    }
    __syncthreads();

    // log-softmax over L = 512 (thread owns l = tid and tid+256)
    const float a0 = s_lds[tid];
    const float a1 = s_lds[tid + 256];
    float mx = fmaxf(a0, a1);
#pragma unroll
    for(int off = 32; off > 0; off >>= 1) mx = fmaxf(mx, __shfl_xor(mx, off, 64));
    if(lane == 0) red[wvl] = mx;
    __syncthreads();
    mx = fmaxf(fmaxf(red[0], red[1]), fmaxf(red[2], red[3]));
    float es = __expf(a0 - mx) + __expf(a1 - mx);
#pragma unroll
    for(int off = 32; off > 0; off >>= 1) es += __shfl_xor(es, off, 64);
    if(lane == 0) red[4 + wvl] = es;
    __syncthreads();
    const float lse = mx + logf(red[4] + red[5] + red[6] + red[7]);
    out[((size_t)tid * NB + myb) * NT + t]         = a0 - lse;
    out[((size_t)(tid + 256) * NB + myb) * NT + t] = a1 - lse;
    __syncthreads();
  }
}

// ---------------------------------------------------------------------------
extern "C" void kernel_launch(void* const* d_in, const int* in_sizes, int n_in,
                              void* d_out, int out_size, void* d_ws, size_t ws_size,
                              hipStream_t stream)
{
  (void)in_sizes; (void)n_in; (void)out_size; (void)ws_size;
  const int*   ids  = (const int*)d_in[0];
  const float* emb  = (const float*)d_in[1];
  const float* eWih = (const float*)d_in[2];
  const float* eWhh = (const float*)d_in[3];
  const float* ebih = (const float*)d_in[4];
  const float* ebhh = (const float*)d_in[5];
  /* d_in[6] = dec_Wih: unused (decoder input is identically zero) */
  const float* dWhh = (const float*)d_in[7];
  const float* dbih = (const float*)d_in[8];
  const float* dbhh = (const float*)d_in[9];
  const float* W1   = (const float*)d_in[10];
  const float* b1   = (const float*)d_in[11];
  const float* W2   = (const float*)d_in[12];
  const float* b2   = (const float*)d_in[13];
  const float* vt   = (const float*)d_in[14];
  const float* vtb  = (const float*)d_in[15];
  const float* h0   = (const float*)d_in[16];

  // workspace: ~27.7 MB (proven envelope). Region X is bf16-emb during enc,
  // then re-used as the decoder's 64 write-once h slots (stamp disambiguates).
  char* ws = (char*)d_ws;
  u16* bl     = (u16*)ws; ws += (size_t)NL * NB * NW * 2;    // blend1 bf16  16.78 MB
  u16* hroll  = (u16*)ws; ws += (size_t)2 * NB * NH * 2;     // enc h ring   0.13 MB
  u16* X      = (u16*)ws; ws += (size_t)10000 * NE * 2;      // emb_b / hdec 5.12 MB
  u16* eWih_b = (u16*)ws; ws += (size_t)4 * NH * NE * 2;     // 1.05 MB
  u16* eWhh_b = (u16*)ws; ws += (size_t)4 * NH * NH * 2;     // 2.10 MB
  u16* dWhh_b = (u16*)ws; ws += (size_t)4 * NH * NH * 2;     // 2.10 MB
  u16* W1_b   = (u16*)ws; ws += (size_t)NW * NH * 2;         // 0.26 MB

  // enc ring slots pre-filled with stamp-1 pattern (first writes use stamp 0)
  hipLaunchKernelGGL(fill_kernel, dim3((2 * NB * NH / 2) / 256), dim3(256), 0, stream,
                     (u32*)hroll, 0x40004000u);
  hipLaunchKernelGGL(cvt_kernel, dim3((10000 * NE + 255) / 256), dim3(256), 0, stream, emb,  X,      10000 * NE);
  hipLaunchKernelGGL(cvt_kernel, dim3((4 * NH * NE + 255) / 256), dim3(256), 0, stream, eWih, eWih_b, 4 * NH * NE);
  hipLaunchKernelGGL(cvt_kernel, dim3((4 * NH * NH + 255) / 256), dim3(256), 0, stream, eWhh, eWhh_b, 4 * NH * NH);
  hipLaunchKernelGGL(cvt_kernel, dim3((4 * NH * NH + 255) / 256), dim3(256), 0, stream, dWhh, dWhh_b, 4 * NH * NH);
  hipLaunchKernelGGL(cvt_kernel, dim3((NW * NH + 255) / 256), dim3(256), 0, stream, W1,   W1_b,   NW * NH);

  hipLaunchKernelGGL(enc_kernel, dim3(32), dim3(256), 0, stream,
                     ids, X, eWih_b, eWhh_b, ebih, ebhh, W1_b, b1, hroll, bl);
  hipLaunchKernelGGL(dec_kernel, dim3(64), dim3(256), 0, stream,
                     dWhh_b, dbih, dbhh, W2, b2, vt, vtb, bl, hroll, h0, X,
                     (float*)d_out);
}

// Round 7
// 15173.322 us; speedup vs baseline: 1.0445x; 1.0018x over previous
//
#include <hip/hip_runtime.h>

#define NB 64      // batch
#define NL 512     // seq len
#define NT 64      // answer len
#define NH 512     // hidden
#define NE 256     // emb dim
#define NW 256     // attention weight dim

typedef __attribute__((ext_vector_type(8))) short bf16x8;
typedef __attribute__((ext_vector_type(4))) float f32x4;
typedef unsigned short u16;
typedef unsigned int u32;
typedef unsigned long long u64;

#define STM 0x4000400040004000ull   // bit14 of each u16 (never set in bf16 of |v|<2)
#define CLRM 0xBFFFBFFFBFFFBFFFull
#define MAGIC 0x600DF00Du

__device__ __forceinline__ float bf2f(u16 v){
  union { u32 u; float f; } x; x.u = ((u32)v) << 16; return x.f;
}
__device__ __forceinline__ u16 f2bf(float f){
  union { float f; u32 u; } x; x.f = f;
  return (u16)((x.u + 0x7FFFu + ((x.u >> 16) & 1u)) >> 16);
}
__device__ __forceinline__ float sigm(float x){ return 1.f / (1.f + __expf(-x)); }
__device__ __forceinline__ float tanh_(float x){ float e = __expf(2.f * x); return 1.f - 2.f / (e + 1.f); }

// device-scope (L3 coherence point) loads/stores — poll-on-data, no fences
__device__ __forceinline__ u64 ald64(const u64* p){
  return __hip_atomic_load(p, __ATOMIC_RELAXED, __HIP_MEMORY_SCOPE_AGENT);
}
__device__ __forceinline__ u32 ald32(const u32* p){
  return __hip_atomic_load(p, __ATOMIC_RELAXED, __HIP_MEMORY_SCOPE_AGENT);
}
__device__ __forceinline__ void ast32(u32* p, u32 v){
  __hip_atomic_store(p, v, __ATOMIC_RELAXED, __HIP_MEMORY_SCOPE_AGENT);
}
__device__ __forceinline__ void ast64(u64* p, u64 v){
  __hip_atomic_store(p, v, __ATOMIC_RELAXED, __HIP_MEMORY_SCOPE_AGENT);
}
__device__ __forceinline__ bf16x8 mk8(u64 a, u64 b){
  union { u64 q[2]; bf16x8 v; } u; u.q[0] = a; u.q[1] = b; return u.v;
}

// DVFS heater: register-only FMA bursts; thread 0 checks done-flags between
// bursts (LDS-broadcast). Purpose: keep the chip's utilization high so sclk
// doesn't sit on the idle floor while the persistent kernels' serial
// recurrence runs on a handful of CUs.
__device__ __forceinline__ void heater(const u32* dflags, int nflags, u32* sink, u32* hstop){
  float a0 = 1.0f + (threadIdx.x & 7) * 0.01f, a1 = 1.1f, a2 = 1.2f, a3 = 1.3f;
  const float c = 1.0000002f, d = 1e-9f;
  if(threadIdx.x == 0) *hstop = 0;
  __syncthreads();
  for(;;){
#pragma unroll
    for(int i = 0; i < 128; ++i){
      a0 = __builtin_fmaf(a0, c, d); a1 = __builtin_fmaf(a1, c, d);
      a2 = __builtin_fmaf(a2, c, d); a3 = __builtin_fmaf(a3, c, d);
    }
    if(threadIdx.x == 0){
      u32 ok = 1;
      for(int q = 0; q < nflags; ++q) ok &= (ald32(dflags + q * 16) == MAGIC) ? 1u : 0u;
      *hstop = ok;
    }
    __syncthreads();
    if(*hstop) break;
    __syncthreads();
  }
  if(a0 == 0.123456f) *sink = (u32)a1;   // never true; defeats DCE
}

__global__ void fill_kernel(u32* p, u32 v){
  p[blockIdx.x * 256 + threadIdx.x] = v;
}

// fp32 -> bf16 (round-to-nearest-even)
__global__ void cvt_kernel(const float* __restrict__ src, u16* __restrict__ dst, int n){
  const int i = blockIdx.x * 256 + threadIdx.x;
  if(i < n) dst[i] = f2bf(src[i]);
}

// ---------------------------------------------------------------------------
// Encoder: 256 blocks x 256 threads. Blocks 0..31 do the real work (identical
// to round 6: 4 independent btile groups of 8 blocks, poll-on-data stamped h,
// 2-slot ring, blend1 fold). Blocks 32..255 run the DVFS heater until the
// 4 per-group done flags are set.
// ---------------------------------------------------------------------------
__global__ void __launch_bounds__(256, 1) enc_kernel(
    const int* __restrict__ ids, const u16* __restrict__ emb,
    const u16* __restrict__ Wih, const u16* __restrict__ Whh,
    const float* __restrict__ bih, const float* __restrict__ bhh,
    const u16* __restrict__ W1,  const float* __restrict__ b1,
    u16* hroll, u16* bl, u32* done)
{
  __shared__ u32 hstop;
  if(blockIdx.x >= 32){
    heater(done, 4, done + 8 * 16, &hstop);
    return;
  }
  const int lane = threadIdx.x & 63;
  const int col  = lane & 15;
  const int quad = lane >> 4;
  const int btile = blockIdx.x & 3;
  const int mtile = (blockIdx.x >> 2) * 4 + (threadIdx.x >> 6);
  const int j  = mtile * 16 + col;        // hidden index within a gate [0,512)
  const int ab = btile * 16 + col;        // A-row (batch) this lane loads

  float bias[4];
  const u16* wh[4];
  const u16* wx[4];
#pragma unroll
  for(int g = 0; g < 4; ++g){
    const int row = g * NH + j;           // PyTorch gate order i,f,g,o
    bias[g] = bih[row] + bhh[row];
    wh[g] = Whh + (size_t)row * NH + quad * 8;
    wx[g] = Wih + (size_t)row * NE + quad * 8;
  }
  const int* idp = ids + ab * NL;         // ids is [B, L]
  const int n1 = mtile * 16 + col;        // blend1 column (mtile<16 only)
  const u16* w1r = W1 + (size_t)(mtile < 16 ? n1 : 0) * NH + quad * 8;
  const float b1f = (mtile < 16) ? b1[n1] : 0.f;
  float creg[4] = {0.f, 0.f, 0.f, 0.f};   // cell state, lane-owned

  u64 hb[32];                             // h_t fragment (stamped-cleaned)
  f32x4 acc[4];

  // x-part of t=0
  {
    const u16* xr = emb + (size_t)idp[0] * NE + quad * 8;
#pragma unroll
    for(int g = 0; g < 4; ++g) acc[g] = (f32x4){0.f, 0.f, 0.f, 0.f};
#pragma unroll
    for(int k0 = 0; k0 < NE; k0 += 32){
      const bf16x8 af = *(const bf16x8*)(xr + k0);
#pragma unroll
      for(int g = 0; g < 4; ++g)
        acc[g] = __builtin_amdgcn_mfma_f32_16x16x32_bf16(af, *(const bf16x8*)(wx[g] + k0), acc[g], 0, 0, 0);
    }
  }

  for(int t = 0; t < NL; ++t){
    // h part (hb = h_{t-1}, loaded by last iteration's poll)
    if(t > 0){
#pragma unroll
      for(int i = 0; i < 16; ++i){
        const bf16x8 af = mk8(hb[2 * i], hb[2 * i + 1]);
#pragma unroll
        for(int g = 0; g < 4; ++g)
          acc[g] = __builtin_amdgcn_mfma_f32_16x16x32_bf16(af, *(const bf16x8*)(wh[g] + 32 * i), acc[g], 0, 0, 0);
      }
    }
    // epilogue: gates -> c (regs); h_t stamped + packed to u64 -> slot t&1
    const u32 st14 = ((u32)((t >> 1) & 1)) << 14;
    u16* ho = hroll + (t & 1) * (NB * NH);
#pragma unroll
    for(int r = 0; r < 4; ++r){
      const float gi = acc[0][r] + bias[0];
      const float gf = acc[1][r] + bias[1];
      const float gg = acc[2][r] + bias[2];
      const float go = acc[3][r] + bias[3];
      creg[r] = sigm(gf) * creg[r] + sigm(gi) * tanh_(gg);
      const u32 stv  = (u32)f2bf(sigm(go) * tanh_(creg[r])) | st14;
      const u32 pair = stv | (((u32)__shfl_xor((int)stv, 1, 64)) << 16);
      const u32 hi   = (u32)__shfl_xor((int)pair, 2, 64);
      if((col & 3) == 0){
        const int row = btile * 16 + quad * 4 + r;
        ast64((u64*)(ho + (size_t)row * NH + mtile * 16 + col),
              (u64)pair | ((u64)hi << 32));
      }
    }
    // overlap: x-part of t+1 while stores become visible
    if(t + 1 < NL){
      const u16* xr = emb + (size_t)idp[t + 1] * NE + quad * 8;
#pragma unroll
      for(int g = 0; g < 4; ++g) acc[g] = (f32x4){0.f, 0.f, 0.f, 0.f};
#pragma unroll
      for(int k0 = 0; k0 < NE; k0 += 32){
        const bf16x8 af = *(const bf16x8*)(xr + k0);
#pragma unroll
        for(int g = 0; g < 4; ++g)
          acc[g] = __builtin_amdgcn_mfma_f32_16x16x32_bf16(af, *(const bf16x8*)(wx[g] + k0), acc[g], 0, 0, 0);
      }
    }
    // poll-on-data: load h_t fragment until every u16 has this step's stamp
    {
      const u16* ha = hroll + (t & 1) * (NB * NH) + (size_t)ab * NH + quad * 8;
      const u64 want = ((t >> 1) & 1) ? STM : 0ull;
      for(;;){
        bool ok = true;
#pragma unroll
        for(int i = 0; i < 16; ++i){
          const u64* p = (const u64*)(ha + 32 * i);
          hb[2 * i]     = ald64(p);
          hb[2 * i + 1] = ald64(p + 1);
          ok = ok && ((hb[2 * i] & STM) == want) && ((hb[2 * i + 1] & STM) == want);
        }
        if(__ballot(ok) == ~0ull) break;
        __builtin_amdgcn_s_sleep(1);
      }
#pragma unroll
      for(int i = 0; i < 32; ++i) hb[i] &= CLRM;
    }
    // blend1[t] fold (normal stores — consumed after kernel boundary)
    if(mtile < 16){
      f32x4 a2 = {0.f, 0.f, 0.f, 0.f};
#pragma unroll
      for(int i = 0; i < 16; ++i)
        a2 = __builtin_amdgcn_mfma_f32_16x16x32_bf16(mk8(hb[2 * i], hb[2 * i + 1]), *(const bf16x8*)(w1r + 32 * i), a2, 0, 0, 0);
#pragma unroll
      for(int r = 0; r < 4; ++r){
        const int b = btile * 16 + quad * 4 + r;
        bl[((size_t)t * NB + b) * NW + n1] = f2bf(a2[r] + b1f);
      }
    }
  }
  if(threadIdx.x == 0 && blockIdx.x < 4)
    ast32(done + btile * 16, MAGIC);
}

// ---------------------------------------------------------------------------
// Decoder: 256 blocks x 256 threads. Blocks 0..63 real (identical to round 6:
// 64 write-once stamped h slots over the dead emb region, producers 0..31,
// per-block attention + log-softmax). Blocks 64..255 run the heater until
// block 0 sets the dec done flag.
// ---------------------------------------------------------------------------
__global__ void __launch_bounds__(256, 1) dec_kernel(
    const u16* __restrict__ Whh, const float* __restrict__ bih, const float* __restrict__ bhh,
    const float* __restrict__ W2, const float* __restrict__ b2,
    const float* __restrict__ vt, const float* __restrict__ vtb,
    const u16* __restrict__ bl,  const u16* __restrict__ hroll,
    const float* __restrict__ h0f,
    u16* hdX, float* out, u32* done)
{
  __shared__ u32 hstop;
  if(blockIdx.x >= 64){
    heater(done + 4 * 16, 1, done + 8 * 16, &hstop);
    return;
  }
  const int tid  = threadIdx.x;
  const int lane = tid & 63;
  const int wvl  = tid >> 6;
  const int col  = lane & 15;
  const int quad = lane >> 4;
  const int myb  = blockIdx.x;
  const bool producer = (blockIdx.x < 32);

  __shared__ u64  hld[NH / 4];   // this block's h row (1 KB)
  __shared__ float u_lds[NW];
  __shared__ float vt_lds[NW];
  __shared__ float s_lds[NL];
  __shared__ float red[8];

  const int gw   = blockIdx.x * 4 + wvl;
  const int btile = gw >> 5;
  const int mtile = gw & 31;
  const int j  = mtile * 16 + col;
  const int ab = btile * 16 + col;
  float bias[4] = {0.f, 0.f, 0.f, 0.f};
  const u16* wh[4] = {Whh, Whh, Whh, Whh};
  float creg[4] = {0.f, 0.f, 0.f, 0.f};
  if(producer){
#pragma unroll
    for(int g = 0; g < 4; ++g){
      const int row = g * NH + j;
      bias[g] = bih[row] + bhh[row];
      wh[g] = Whh + (size_t)row * NH + quad * 8;
    }
    // c0 = enc h_511: hroll slot 511&1 == 1, stamped with (511>>1)&1 == 1
#pragma unroll
    for(int r = 0; r < 4; ++r){
      const int ci = (btile * 16 + quad * 4 + r) * NH + j;
      creg[r] = bf2f((u16)(hroll[(NB * NH) + ci] & 0xBFFFu));
    }
  }
  vt_lds[tid] = vt[tid];
  const float vtbf = vtb[0];
  const float* w2r = W2 + (size_t)tid * NH;
  const float b2f = b2[tid];

  for(int t = 0; t < NT; ++t){
    if(producer){
      f32x4 z = {0.f, 0.f, 0.f, 0.f};
      f32x4 acc[4] = {z, z, z, z};
      if(t == 0){
        // h_{-1} = h0 (fp32, convert in regs)
        const float* hp = h0f + (size_t)ab * NH + quad * 8;
#pragma unroll
        for(int i = 0; i < 16; ++i){
          const f32x4 a0 = *(const f32x4*)(hp + 32 * i);
          const f32x4 a1 = *(const f32x4*)(hp + 32 * i + 4);
          bf16x8 af;
#pragma unroll
          for(int q = 0; q < 4; ++q){ af[q] = (short)f2bf(a0[q]); af[q + 4] = (short)f2bf(a1[q]); }
#pragma unroll
          for(int g = 0; g < 4; ++g)
            acc[g] = __builtin_amdgcn_mfma_f32_16x16x32_bf16(af, *(const bf16x8*)(wh[g] + 32 * i), acc[g], 0, 0, 0);
        }
      } else {
        // poll-on-data: slot t (stamp always 1)
        u64 hb[32];
        const u16* ha = hdX + (size_t)(t - 1) * (NB * NH) + (size_t)ab * NH + quad * 8;
        for(;;){
          bool ok = true;
#pragma unroll
          for(int i = 0; i < 16; ++i){
            const u64* p = (const u64*)(ha + 32 * i);
            hb[2 * i]     = ald64(p);
            hb[2 * i + 1] = ald64(p + 1);
            ok = ok && ((hb[2 * i] & STM) == STM) && ((hb[2 * i + 1] & STM) == STM);
          }
          if(__ballot(ok) == ~0ull) break;
          __builtin_amdgcn_s_sleep(1);
        }
#pragma unroll
        for(int i = 0; i < 16; ++i){
          const bf16x8 af = mk8(hb[2 * i] & CLRM, hb[2 * i + 1] & CLRM);
#pragma unroll
          for(int g = 0; g < 4; ++g)
            acc[g] = __builtin_amdgcn_mfma_f32_16x16x32_bf16(af, *(const bf16x8*)(wh[g] + 32 * i), acc[g], 0, 0, 0);
        }
      }
      // epilogue: store h_t stamped into slot t+1
      u16* hn = hdX + (size_t)t * (NB * NH);
#pragma unroll
      for(int r = 0; r < 4; ++r){
        const float gi = acc[0][r] + bias[0];
        const float gf = acc[1][r] + bias[1];
        const float gg = acc[2][r] + bias[2];
        const float go = acc[3][r] + bias[3];
        creg[r] = sigm(gf) * creg[r] + sigm(gi) * tanh_(gg);
        const u32 stv  = (u32)f2bf(sigm(go) * tanh_(creg[r])) | 0x4000u;
        const u32 pair = stv | (((u32)__shfl_xor((int)stv, 1, 64)) << 16);
        const u32 hi   = (u32)__shfl_xor((int)pair, 2, 64);
        if((col & 3) == 0){
          const int row = btile * 16 + quad * 4 + r;
          ast64((u64*)(hn + (size_t)row * NH + mtile * 16 + col),
                (u64)pair | ((u64)hi << 32));
        }
      }
    }

    // ---- all blocks: wave 0 polls row myb of slot t+1, stages into LDS ----
    if(wvl == 0){
      const u16* hr = hdX + (size_t)t * (NB * NH) + (size_t)myb * NH;
      const u64* hp = (const u64*)hr;
      u64 a, b;
      for(;;){
        a = ald64(hp + lane);
        b = ald64(hp + 64 + lane);
        const bool ok = ((a & STM) == STM) && ((b & STM) == STM);
        if(__ballot(ok) == ~0ull) break;
        __builtin_amdgcn_s_sleep(1);
      }
      hld[lane]      = a & CLRM;
      hld[lane + 64] = b & CLRM;
    }
    __syncthreads();

    // u[tid] = b2[tid] + h . W2[tid,:]
    {
      float s = b2f;
#pragma unroll 8
      for(int kk = 0; kk < NH / 4; ++kk){
        const u64 v = hld[kk];
        s += bf2f((u16)(v      )) * w2r[kk * 4    ];
        s += bf2f((u16)(v >> 16)) * w2r[kk * 4 + 1];
        s += bf2f((u16)(v >> 32)) * w2r[kk * 4 + 2];
        s += bf2f((u16)(v >> 48)) * w2r[kk * 4 + 3];
      }
      u_lds[tid] = s;
    }
    __syncthreads();

    for(int l = wvl; l < NL; l += 4){
      const u16* br = bl + (size_t)(l * NB + myb) * NW;
      float p = 0.f;
#pragma unroll
      for(int q = 0; q < 4; ++q){
        const int w = lane + 64 * q;
        p += vt_lds[w] * tanh_(bf2f(br[w]) + u_lds[w]);
      }
#pragma unroll
      for(int off = 32; off > 0; off >>= 1) p += __shfl_xor(p, off, 64);
      if(lane == 0) s_lds[l] = p + vtbf;
    }
    __syncthreads();

    // log-softmax over L = 512 (thread owns l = tid and tid+256)
    const float a0 = s_lds[tid];
    const float a1 = s_lds[tid + 256];
    float mx = fmaxf(a0, a1);
#pragma unroll
    for(int off = 32; off > 0; off >>= 1) mx = fmaxf(mx, __shfl_xor(mx, off, 64));
    if(lane == 0) red[wvl] = mx;
    __syncthreads();
    mx = fmaxf(fmaxf(red[0], red[1]), fmaxf(red[2], red[3]));
    float es = __expf(a0 - mx) + __expf(a1 - mx);
#pragma unroll
    for(int off = 32; off > 0; off >>= 1) es += __shfl_xor(es, off, 64);
    if(lane == 0) red[4 + wvl] = es;
    __syncthreads();
    const float lse = mx + logf(red[4] + red[5] + red[6] + red[7]);
    out[((size_t)tid * NB + myb) * NT + t]         = a0 - lse;
    out[((size_t)(tid + 256) * NB + myb) * NT + t] = a1 - lse;
    __syncthreads();
  }
  if(tid == 0 && blockIdx.x == 0)
    ast32(done + 4 * 16, MAGIC);
}

// ---------------------------------------------------------------------------
extern "C" void kernel_launch(void* const* d_in, const int* in_sizes, int n_in,
                              void* d_out, int out_size, void* d_ws, size_t ws_size,
                              hipStream_t stream)
{
  (void)in_sizes; (void)n_in; (void)out_size; (void)ws_size;
  const int*   ids  = (const int*)d_in[0];
  const float* emb  = (const float*)d_in[1];
  const float* eWih = (const float*)d_in[2];
  const float* eWhh = (const float*)d_in[3];
  const float* ebih = (const float*)d_in[4];
  const float* ebhh = (const float*)d_in[5];
  /* d_in[6] = dec_Wih: unused (decoder input is identically zero) */
  const float* dWhh = (const float*)d_in[7];
  const float* dbih = (const float*)d_in[8];
  const float* dbhh = (const float*)d_in[9];
  const float* W1   = (const float*)d_in[10];
  const float* b1   = (const float*)d_in[11];
  const float* W2   = (const float*)d_in[12];
  const float* b2   = (const float*)d_in[13];
  const float* vt   = (const float*)d_in[14];
  const float* vtb  = (const float*)d_in[15];
  const float* h0   = (const float*)d_in[16];

  // workspace: ~27.7 MB (proven envelope). Region X is bf16-emb during enc,
  // then re-used as the decoder's 64 write-once h slots (stamp disambiguates).
  char* ws = (char*)d_ws;
  u16* bl     = (u16*)ws; ws += (size_t)NL * NB * NW * 2;    // blend1 bf16  16.78 MB
  u16* hroll  = (u16*)ws; ws += (size_t)2 * NB * NH * 2;     // enc h ring   0.13 MB
  u16* X      = (u16*)ws; ws += (size_t)10000 * NE * 2;      // emb_b / hdec 5.12 MB
  u16* eWih_b = (u16*)ws; ws += (size_t)4 * NH * NE * 2;     // 1.05 MB
  u16* eWhh_b = (u16*)ws; ws += (size_t)4 * NH * NH * 2;     // 2.10 MB
  u16* dWhh_b = (u16*)ws; ws += (size_t)4 * NH * NH * 2;     // 2.10 MB
  u16* W1_b   = (u16*)ws; ws += (size_t)NW * NH * 2;         // 0.26 MB
  u32* done   = (u32*)ws; ws += 1024;                        // done flags (64B lines)

  // enc ring slots pre-filled with stamp-1 pattern; done flags zeroed
  hipLaunchKernelGGL(fill_kernel, dim3((2 * NB * NH / 2) / 256), dim3(256), 0, stream,
                     (u32*)hroll, 0x40004000u);
  hipLaunchKernelGGL(fill_kernel, dim3(1), dim3(256), 0, stream, done, 0u);
  hipLaunchKernelGGL(cvt_kernel, dim3((10000 * NE + 255) / 256), dim3(256), 0, stream, emb,  X,      10000 * NE);
  hipLaunchKernelGGL(cvt_kernel, dim3((4 * NH * NE + 255) / 256), dim3(256), 0, stream, eWih, eWih_b, 4 * NH * NE);
  hipLaunchKernelGGL(cvt_kernel, dim3((4 * NH * NH + 255) / 256), dim3(256), 0, stream, eWhh, eWhh_b, 4 * NH * NH);
  hipLaunchKernelGGL(cvt_kernel, dim3((4 * NH * NH + 255) / 256), dim3(256), 0, stream, dWhh, dWhh_b, 4 * NH * NH);
  hipLaunchKernelGGL(cvt_kernel, dim3((NW * NH + 255) / 256), dim3(256), 0, stream, W1,   W1_b,   NW * NH);

  hipLaunchKernelGGL(enc_kernel, dim3(256), dim3(256), 0, stream,
                     ids, X, eWih_b, eWhh_b, ebih, ebhh, W1_b, b1, hroll, bl, done);
  hipLaunchKernelGGL(dec_kernel, dim3(256), dim3(256), 0, stream,
                     dWhh_b, dbih, dbhh, W2, b2, vt, vtb, bl, hroll, h0, X,
                     (float*)d_out, done);
}

// Round 8
// 14477.130 us; speedup vs baseline: 1.0947x; 1.0481x over previous
//
#include <hip/hip_runtime.h>

#define NB 64      // batch
#define NL 512     // seq len
#define NT 64      // answer len
#define NH 512     // hidden
#define NE 256     // emb dim
#define NW 256     // attention weight dim

typedef __attribute__((ext_vector_type(8))) short bf16x8;
typedef __attribute__((ext_vector_type(4))) float f32x4;
typedef unsigned short u16;
typedef unsigned int u32;
typedef unsigned long long u64;

#define STM 0x4000400040004000ull   // bit14 of each u16 (never set in bf16 of |v|<2)
#define CLRM 0xBFFFBFFFBFFFBFFFull

__device__ __forceinline__ float bf2f(u16 v){
  union { u32 u; float f; } x; x.u = ((u32)v) << 16; return x.f;
}
__device__ __forceinline__ u16 f2bf(float f){
  union { float f; u32 u; } x; x.f = f;
  return (u16)((x.u + 0x7FFFu + ((x.u >> 16) & 1u)) >> 16);
}
__device__ __forceinline__ float sigm(float x){ return 1.f / (1.f + __expf(-x)); }
__device__ __forceinline__ float tanh_(float x){ float e = __expf(2.f * x); return 1.f - 2.f / (e + 1.f); }

// device-scope (L3 coherence point) loads/stores — poll-on-data, no fences
__device__ __forceinline__ u64 ald64(const u64* p){
  return __hip_atomic_load(p, __ATOMIC_RELAXED, __HIP_MEMORY_SCOPE_AGENT);
}
__device__ __forceinline__ void ast64(u64* p, u64 v){
  __hip_atomic_store(p, v, __ATOMIC_RELAXED, __HIP_MEMORY_SCOPE_AGENT);
}
__device__ __forceinline__ bf16x8 mk8(u64 a, u64 b){
  union { u64 q[2]; bf16x8 v; } u; u.q[0] = a; u.q[1] = b; return u.v;
}

__global__ void fill_kernel(u32* p, u32 v){
  p[blockIdx.x * 256 + threadIdx.x] = v;
}

// fp32 -> bf16 (round-to-nearest-even)
__global__ void cvt_kernel(const float* __restrict__ src, u16* __restrict__ dst, int n){
  const int i = blockIdx.x * 256 + threadIdx.x;
  if(i < n) dst[i] = f2bf(src[i]);
}

// ---------------------------------------------------------------------------
// Encoder: persistent, 32 blocks x 256 threads, 4 independent btile groups of
// 8 blocks. Wave computes 16(batch) x 16(hidden) of all 4 gates; cell state
// in registers; Whh B-fragments REGISTER-RESIDENT (whr[16][4], 256 VGPRs) —
// zero per-step L2 weight traffic for the h-part. h in a 2-slot ring; each
// stored u16 stamped in bit14 with parity (t>>1)&1; consumers poll the data
// itself (one visibility hop). Overwrite-safe by ring depth 2.
// ---------------------------------------------------------------------------
__global__ void __launch_bounds__(256, 1) enc_kernel(
    const int* __restrict__ ids, const u16* __restrict__ emb,
    const u16* __restrict__ Wih, const u16* __restrict__ Whh,
    const float* __restrict__ bih, const float* __restrict__ bhh,
    const u16* __restrict__ W1,  const float* __restrict__ b1,
    u16* hroll, u16* bl)
{
  const int lane = threadIdx.x & 63;
  const int col  = lane & 15;
  const int quad = lane >> 4;
  const int btile = blockIdx.x & 3;
  const int mtile = (blockIdx.x >> 2) * 4 + (threadIdx.x >> 6);
  const int j  = mtile * 16 + col;        // hidden index within a gate [0,512)
  const int ab = btile * 16 + col;        // A-row (batch) this lane loads

  float bias[4];
  const u16* wx[4];
  bf16x8 whr[16][4];                      // register-resident Whh fragments
#pragma unroll
  for(int g = 0; g < 4; ++g){
    const int row = g * NH + j;           // PyTorch gate order i,f,g,o
    bias[g] = bih[row] + bhh[row];
    wx[g] = Wih + (size_t)row * NE + quad * 8;
    const u16* whp = Whh + (size_t)row * NH + quad * 8;
#pragma unroll
    for(int i = 0; i < 16; ++i)
      whr[i][g] = *(const bf16x8*)(whp + 32 * i);
  }
  const int* idp = ids + ab * NL;         // ids is [B, L]
  const int n1 = mtile * 16 + col;        // blend1 column (mtile<16 only)
  const u16* w1r = W1 + (size_t)(mtile < 16 ? n1 : 0) * NH + quad * 8;
  const float b1f = (mtile < 16) ? b1[n1] : 0.f;
  float creg[4] = {0.f, 0.f, 0.f, 0.f};   // cell state, lane-owned

  u64 hb[32];                             // h_t fragment (stamped-cleaned)
  f32x4 acc[4];

  // x-part of t=0
  {
    const u16* xr = emb + (size_t)idp[0] * NE + quad * 8;
#pragma unroll
    for(int g = 0; g < 4; ++g) acc[g] = (f32x4){0.f, 0.f, 0.f, 0.f};
#pragma unroll
    for(int k0 = 0; k0 < NE; k0 += 32){
      const bf16x8 af = *(const bf16x8*)(xr + k0);
#pragma unroll
      for(int g = 0; g < 4; ++g)
        acc[g] = __builtin_amdgcn_mfma_f32_16x16x32_bf16(af, *(const bf16x8*)(wx[g] + k0), acc[g], 0, 0, 0);
    }
  }

  for(int t = 0; t < NL; ++t){
    // h part (hb = h_{t-1}, loaded by last iteration's poll) — all-register
    if(t > 0){
#pragma unroll
      for(int i = 0; i < 16; ++i){
        const bf16x8 af = mk8(hb[2 * i], hb[2 * i + 1]);
#pragma unroll
        for(int g = 0; g < 4; ++g)
          acc[g] = __builtin_amdgcn_mfma_f32_16x16x32_bf16(af, whr[i][g], acc[g], 0, 0, 0);
      }
    }
    // epilogue: gates -> c (regs); h_t stamped + packed to u64 -> slot t&1
    const u32 st14 = ((u32)((t >> 1) & 1)) << 14;
    u16* ho = hroll + (t & 1) * (NB * NH);
#pragma unroll
    for(int r = 0; r < 4; ++r){
      const float gi = acc[0][r] + bias[0];
      const float gf = acc[1][r] + bias[1];
      const float gg = acc[2][r] + bias[2];
      const float go = acc[3][r] + bias[3];
      creg[r] = sigm(gf) * creg[r] + sigm(gi) * tanh_(gg);
      const u32 stv  = (u32)f2bf(sigm(go) * tanh_(creg[r])) | st14;
      const u32 pair = stv | (((u32)__shfl_xor((int)stv, 1, 64)) << 16);
      const u32 hi   = (u32)__shfl_xor((int)pair, 2, 64);
      if((col & 3) == 0){
        const int row = btile * 16 + quad * 4 + r;
        ast64((u64*)(ho + (size_t)row * NH + mtile * 16 + col),
              (u64)pair | ((u64)hi << 32));
      }
    }
    // overlap: x-part of t+1 while stores become visible
    if(t + 1 < NL){
      const u16* xr = emb + (size_t)idp[t + 1] * NE + quad * 8;
#pragma unroll
      for(int g = 0; g < 4; ++g) acc[g] = (f32x4){0.f, 0.f, 0.f, 0.f};
#pragma unroll
      for(int k0 = 0; k0 < NE; k0 += 32){
        const bf16x8 af = *(const bf16x8*)(xr + k0);
#pragma unroll
        for(int g = 0; g < 4; ++g)
          acc[g] = __builtin_amdgcn_mfma_f32_16x16x32_bf16(af, *(const bf16x8*)(wx[g] + k0), acc[g], 0, 0, 0);
      }
    }
    // poll-on-data: load h_t fragment until every u16 has this step's stamp
    {
      const u16* ha = hroll + (t & 1) * (NB * NH) + (size_t)ab * NH + quad * 8;
      const u64 want = ((t >> 1) & 1) ? STM : 0ull;
      for(;;){
        bool ok = true;
#pragma unroll
        for(int i = 0; i < 16; ++i){
          const u64* p = (const u64*)(ha + 32 * i);
          hb[2 * i]     = ald64(p);
          hb[2 * i + 1] = ald64(p + 1);
          ok = ok && ((hb[2 * i] & STM) == want) && ((hb[2 * i + 1] & STM) == want);
        }
        if(__ballot(ok) == ~0ull) break;
        __builtin_amdgcn_s_sleep(1);
      }
#pragma unroll
      for(int i = 0; i < 32; ++i) hb[i] &= CLRM;
    }
    // blend1[t] fold (normal stores — consumed after kernel boundary)
    if(mtile < 16){
      f32x4 a2 = {0.f, 0.f, 0.f, 0.f};
#pragma unroll
      for(int i = 0; i < 16; ++i)
        a2 = __builtin_amdgcn_mfma_f32_16x16x32_bf16(mk8(hb[2 * i], hb[2 * i + 1]), *(const bf16x8*)(w1r + 32 * i), a2, 0, 0, 0);
#pragma unroll
      for(int r = 0; r < 4; ++r){
        const int b = btile * 16 + quad * 4 + r;
        bl[((size_t)t * NB + b) * NW + n1] = f2bf(a2[r] + b1f);
      }
    }
  }
}

// ---------------------------------------------------------------------------
// Decoder: persistent, 64 blocks x 256 threads. 64 write-once h slots (slot
// t+1 = h_t), stamp bit14 == 1; initial slot bytes are leftover bf16 emb
// (|v|<2 => stamp 0), so no init needed. t=0 reads fp32 h0 directly.
// Producers (blocks 0..31, register-resident dWhh) poll slot t, compute,
// store slot t+1. All 64 blocks: wave 0 polls row myb of slot t+1, stages
// into LDS; attention + log-softmax; write out column t.
// ---------------------------------------------------------------------------
__global__ void __launch_bounds__(256, 1) dec_kernel(
    const u16* __restrict__ Whh, const float* __restrict__ bih, const float* __restrict__ bhh,
    const float* __restrict__ W2, const float* __restrict__ b2,
    const float* __restrict__ vt, const float* __restrict__ vtb,
    const u16* __restrict__ bl,  const u16* __restrict__ hroll,
    const float* __restrict__ h0f,
    u16* hdX, float* out)
{
  const int tid  = threadIdx.x;
  const int lane = tid & 63;
  const int wvl  = tid >> 6;
  const int col  = lane & 15;
  const int quad = lane >> 4;
  const int myb  = blockIdx.x;
  const bool producer = (blockIdx.x < 32);

  __shared__ u64  hld[NH / 4];   // this block's h row (1 KB)
  __shared__ float u_lds[NW];
  __shared__ float vt_lds[NW];
  __shared__ float s_lds[NL];
  __shared__ float red[8];

  const int gw   = blockIdx.x * 4 + wvl;
  const int btile = gw >> 5;
  const int mtile = gw & 31;
  const int j  = mtile * 16 + col;
  const int ab = btile * 16 + col;
  float bias[4] = {0.f, 0.f, 0.f, 0.f};
  bf16x8 whr[16][4];
  float creg[4] = {0.f, 0.f, 0.f, 0.f};
  if(producer){
#pragma unroll
    for(int g = 0; g < 4; ++g){
      const int row = g * NH + j;
      bias[g] = bih[row] + bhh[row];
      const u16* whp = Whh + (size_t)row * NH + quad * 8;
#pragma unroll
      for(int i = 0; i < 16; ++i)
        whr[i][g] = *(const bf16x8*)(whp + 32 * i);
    }
    // c0 = enc h_511: hroll slot 511&1 == 1, stamped with (511>>1)&1 == 1
#pragma unroll
    for(int r = 0; r < 4; ++r){
      const int ci = (btile * 16 + quad * 4 + r) * NH + j;
      creg[r] = bf2f((u16)(hroll[(NB * NH) + ci] & 0xBFFFu));
    }
  }
  vt_lds[tid] = vt[tid];
  const float vtbf = vtb[0];
  const float* w2r = W2 + (size_t)tid * NH;
  const float b2f = b2[tid];

  for(int t = 0; t < NT; ++t){
    if(producer){
      f32x4 z = {0.f, 0.f, 0.f, 0.f};
      f32x4 acc[4] = {z, z, z, z};
      if(t == 0){
        // h_{-1} = h0 (fp32, convert in regs)
        const float* hp = h0f + (size_t)ab * NH + quad * 8;
#pragma unroll
        for(int i = 0; i < 16; ++i){
          const f32x4 a0 = *(const f32x4*)(hp + 32 * i);
          const f32x4 a1 = *(const f32x4*)(hp + 32 * i + 4);
          bf16x8 af;
#pragma unroll
          for(int q = 0; q < 4; ++q){ af[q] = (short)f2bf(a0[q]); af[q + 4] = (short)f2bf(a1[q]); }
#pragma unroll
          for(int g = 0; g < 4; ++g)
            acc[g] = __builtin_amdgcn_mfma_f32_16x16x32_bf16(af, whr[i][g], acc[g], 0, 0, 0);
        }
      } else {
        // poll-on-data: slot t (stamp always 1)
        u64 hb[32];
        const u16* ha = hdX + (size_t)(t - 1) * (NB * NH) + (size_t)ab * NH + quad * 8;
        for(;;){
          bool ok = true;
#pragma unroll
          for(int i = 0; i < 16; ++i){
            const u64* p = (const u64*)(ha + 32 * i);
            hb[2 * i]     = ald64(p);
            hb[2 * i + 1] = ald64(p + 1);
            ok = ok && ((hb[2 * i] & STM) == STM) && ((hb[2 * i + 1] & STM) == STM);
          }
          if(__ballot(ok) == ~0ull) break;
          __builtin_amdgcn_s_sleep(1);
        }
#pragma unroll
        for(int i = 0; i < 16; ++i){
          const bf16x8 af = mk8(hb[2 * i] & CLRM, hb[2 * i + 1] & CLRM);
#pragma unroll
          for(int g = 0; g < 4; ++g)
            acc[g] = __builtin_amdgcn_mfma_f32_16x16x32_bf16(af, whr[i][g], acc[g], 0, 0, 0);
        }
      }
      // epilogue: store h_t stamped into slot t+1
      u16* hn = hdX + (size_t)t * (NB * NH);
#pragma unroll
      for(int r = 0; r < 4; ++r){
        const float gi = acc[0][r] + bias[0];
        const float gf = acc[1][r] + bias[1];
        const float gg = acc[2][r] + bias[2];
        const float go = acc[3][r] + bias[3];
        creg[r] = sigm(gf) * creg[r] + sigm(gi) * tanh_(gg);
        const u32 stv  = (u32)f2bf(sigm(go) * tanh_(creg[r])) | 0x4000u;
        const u32 pair = stv | (((u32)__shfl_xor((int)stv, 1, 64)) << 16);
        const u32 hi   = (u32)__shfl_xor((int)pair, 2, 64);
        if((col & 3) == 0){
          const int row = btile * 16 + quad * 4 + r;
          ast64((u64*)(hn + (size_t)row * NH + mtile * 16 + col),
                (u64)pair | ((u64)hi << 32));
        }
      }
    }

    // ---- all blocks: wave 0 polls row myb of slot t+1, stages into LDS ----
    if(wvl == 0){
      const u16* hr = hdX + (size_t)t * (NB * NH) + (size_t)myb * NH;
      const u64* hp = (const u64*)hr;
      u64 a, b;
      for(;;){
        a = ald64(hp + lane);
        b = ald64(hp + 64 + lane);
        const bool ok = ((a & STM) == STM) && ((b & STM) == STM);
        if(__ballot(ok) == ~0ull) break;
        __builtin_amdgcn_s_sleep(1);
      }
      hld[lane]      = a & CLRM;
      hld[lane + 64] = b & CLRM;
    }
    __syncthreads();

    // u[tid] = b2[tid] + h . W2[tid,:]
    {
      float s = b2f;
#pragma unroll 8
      for(int kk = 0; kk < NH / 4; ++kk){
        const u64 v = hld[kk];
        s += bf2f((u16)(v      )) * w2r[kk * 4    ];
        s += bf2f((u16)(v >> 16)) * w2r[kk * 4 + 1];
        s += bf2f((u16)(v >> 32)) * w2r[kk * 4 + 2];
        s += bf2f((u16)(v >> 48)) * w2r[kk * 4 + 3];
      }
      u_lds[tid] = s;
    }
    __syncthreads();

    for(int l = wvl; l < NL; l += 4){
      const u16* br = bl + (size_t)(l * NB + myb) * NW;
      float p = 0.f;
#pragma unroll
      for(int q = 0; q < 4; ++q){
        const int w = lane + 64 * q;
        p += vt_lds[w] * tanh_(bf2f(br[w]) + u_lds[w]);
      }
#pragma unroll
      for(int off = 32; off > 0; off >>= 1) p += __shfl_xor(p, off, 64);
      if(lane == 0) s_lds[l] = p + vtbf;
    }
    __syncthreads();

    // log-softmax over L = 512 (thread owns l = tid and tid+256)
    const float a0 = s_lds[tid];
    const float a1 = s_lds[tid + 256];
    float mx = fmaxf(a0, a1);
#pragma unroll
    for(int off = 32; off > 0; off >>= 1) mx = fmaxf(mx, __shfl_xor(mx, off, 64));
    if(lane == 0) red[wvl] = mx;
    __syncthreads();
    mx = fmaxf(fmaxf(red[0], red[1]), fmaxf(red[2], red[3]));
    float es = __expf(a0 - mx) + __expf(a1 - mx);
#pragma unroll
    for(int off = 32; off > 0; off >>= 1) es += __shfl_xor(es, off, 64);
    if(lane == 0) red[4 + wvl] = es;
    __syncthreads();
    const float lse = mx + logf(red[4] + red[5] + red[6] + red[7]);
    out[((size_t)tid * NB + myb) * NT + t]         = a0 - lse;
    out[((size_t)(tid + 256) * NB + myb) * NT + t] = a1 - lse;
    __syncthreads();
  }
}

// ---------------------------------------------------------------------------
extern "C" void kernel_launch(void* const* d_in, const int* in_sizes, int n_in,
                              void* d_out, int out_size, void* d_ws, size_t ws_size,
                              hipStream_t stream)
{
  (void)in_sizes; (void)n_in; (void)out_size; (void)ws_size;
  const int*   ids  = (const int*)d_in[0];
  const float* emb  = (const float*)d_in[1];
  const float* eWih = (const float*)d_in[2];
  const float* eWhh = (const float*)d_in[3];
  const float* ebih = (const float*)d_in[4];
  const float* ebhh = (const float*)d_in[5];
  /* d_in[6] = dec_Wih: unused (decoder input is identically zero) */
  const float* dWhh = (const float*)d_in[7];
  const float* dbih = (const float*)d_in[8];
  const float* dbhh = (const float*)d_in[9];
  const float* W1   = (const float*)d_in[10];
  const float* b1   = (const float*)d_in[11];
  const float* W2   = (const float*)d_in[12];
  const float* b2   = (const float*)d_in[13];
  const float* vt   = (const float*)d_in[14];
  const float* vtb  = (const float*)d_in[15];
  const float* h0   = (const float*)d_in[16];

  // workspace: ~27.7 MB. Region X is bf16-emb during enc, then re-used as the
  // decoder's 64 write-once h slots (stamp disambiguates).
  char* ws = (char*)d_ws;
  u16* bl     = (u16*)ws; ws += (size_t)NL * NB * NW * 2;    // blend1 bf16  16.78 MB
  u16* hroll  = (u16*)ws; ws += (size_t)2 * NB * NH * 2;     // enc h ring   0.13 MB
  u16* X      = (u16*)ws; ws += (size_t)10000 * NE * 2;      // emb_b / hdec 5.12 MB
  u16* eWih_b = (u16*)ws; ws += (size_t)4 * NH * NE * 2;     // 1.05 MB
  u16* eWhh_b = (u16*)ws; ws += (size_t)4 * NH * NH * 2;     // 2.10 MB
  u16* dWhh_b = (u16*)ws; ws += (size_t)4 * NH * NH * 2;     // 2.10 MB
  u16* W1_b   = (u16*)ws; ws += (size_t)NW * NH * 2;         // 0.26 MB

  // enc ring slots pre-filled with stamp-1 pattern (first writes use stamp 0)
  hipLaunchKernelGGL(fill_kernel, dim3((2 * NB * NH / 2) / 256), dim3(256), 0, stream,
                     (u32*)hroll, 0x40004000u);
  hipLaunchKernelGGL(cvt_kernel, dim3((10000 * NE + 255) / 256), dim3(256), 0, stream, emb,  X,      10000 * NE);
  hipLaunchKernelGGL(cvt_kernel, dim3((4 * NH * NE + 255) / 256), dim3(256), 0, stream, eWih, eWih_b, 4 * NH * NE);
  hipLaunchKernelGGL(cvt_kernel, dim3((4 * NH * NH + 255) / 256), dim3(256), 0, stream, eWhh, eWhh_b, 4 * NH * NH);
  hipLaunchKernelGGL(cvt_kernel, dim3((4 * NH * NH + 255) / 256), dim3(256), 0, stream, dWhh, dWhh_b, 4 * NH * NH);
  hipLaunchKernelGGL(cvt_kernel, dim3((NW * NH + 255) / 256), dim3(256), 0, stream, W1,   W1_b,   NW * NH);

  hipLaunchKernelGGL(enc_kernel, dim3(32), dim3(256), 0, stream,
                     ids, X, eWih_b, eWhh_b, ebih, ebhh, W1_b, b1, hroll, bl);
  hipLaunchKernelGGL(dec_kernel, dim3(64), dim3(256), 0, stream,
                     dWhh_b, dbih, dbhh, W2, b2, vt, vtb, bl, hroll, h0, X,
                     (float*)d_out);
}